// Round 3
// baseline (722.289 us; speedup 1.0000x reference)
//
#include <hip/hip_runtime.h>
#include <hip/hip_bf16.h>
#include <stdint.h>

#define NP 409600
#define HG 640
#define WG 640
#define HW (HG*WG)

typedef __bf16 bf16x8 __attribute__((ext_vector_type(8)));
typedef float f32x4 __attribute__((ext_vector_type(4)));

// ---------------- prep kernels ----------------

// scatter point index into dense grid AND emit packed coords (b<<20|y<<10|x)
__global__ void scatter_kernel(const int* __restrict__ coords, int* __restrict__ sgrid,
                               int* __restrict__ pc) {
    int i = blockIdx.x * 256 + threadIdx.x;   // grid sized exactly NP
    int b = coords[3*i], y = coords[3*i+1], x = coords[3*i+2];
    sgrid[b*HW + y*WG + x] = i;
    pc[i] = (b << 20) | (y << 10) | x;
}

__global__ void cast_feat_kernel(const float* __restrict__ f, __hip_bfloat16* __restrict__ fb) {
    long i = (long)(blockIdx.x * 256 + threadIdx.x) * 8;   // grid covers NP*64 exactly
    float4 a = *(const float4*)(f + i);
    float4 b = *(const float4*)(f + i + 4);
    union { uint4 q; __hip_bfloat16 h[8]; } u;
    u.h[0] = __float2bfloat16(a.x); u.h[1] = __float2bfloat16(a.y);
    u.h[2] = __float2bfloat16(a.z); u.h[3] = __float2bfloat16(a.w);
    u.h[4] = __float2bfloat16(b.x); u.h[5] = __float2bfloat16(b.y);
    u.h[6] = __float2bfloat16(b.z); u.h[7] = __float2bfloat16(b.w);
    *(uint4*)(fb + i) = u.q;
}

// weights pre-cast to bf16, transposed to [tap][n=out_ch][k=in_ch]
__global__ void cast_w_kernel(const float* __restrict__ w1, const float* __restrict__ w2,
                              const float* __restrict__ wd,
                              __hip_bfloat16* __restrict__ wc1, __hip_bfloat16* __restrict__ wc2) {
    int i = blockIdx.x * 256 + threadIdx.x;   // grid = 77824 threads exactly
    if (i < 9*4096) {
        int t = i >> 12, r = i & 4095, n = r >> 6, k = r & 63;
        wc1[i] = __float2bfloat16(w1[(t << 12) + (k << 6) + n]);
    }
    int j = i - 9*4096;
    if (j >= 0 && j < 10*4096) {
        int t = j >> 12, r = j & 4095, n = r >> 6, k = r & 63;
        float v = (t < 9) ? w2[(t << 12) + (k << 6) + n] : wd[(k << 6) + n];
        wc2[j] = __float2bfloat16(v);
    }
}

// ---------------- gather-GEMM conv kernel (software-pipelined) ----------------
// Tile: 128 rows x 64 cols, 256 threads = 4 waves.
// Per tap: [barrier] -> LDS store (prefetched regs) -> [barrier] -> issue
// prefetch for tap t+1 -> MFMA tap t. Gather latency hides behind MFMA.
// Neighbor grid lookups all issued at block start (no per-tap index chain).
// A: A[m=lane&15][k=quad*8+j]; B: B[k][n=lane&15]; D: D[row=quad*4+reg][col=lane&15].

#define LDA 72
#define LDB 72

template<int NTAP, bool FINAL>
__launch_bounds__(256)
__global__ void conv_kernel(const __hip_bfloat16* __restrict__ src,
                            const __hip_bfloat16* __restrict__ idsrc,
                            const int* __restrict__ pc,
                            const int* __restrict__ sgrid,
                            const __hip_bfloat16* __restrict__ wT,   // [NTAP][64][64] (n,k)
                            const float* __restrict__ bias,
                            __hip_bfloat16* __restrict__ out_bf,
                            float* __restrict__ out_f) {
    __shared__ __align__(16) __hip_bfloat16 As[128 * LDA];
    __shared__ __align__(16) __hip_bfloat16 Bs[64 * LDB];

    const int tid  = threadIdx.x;
    const int base = blockIdx.x * 128;
    const int wave = tid >> 6, lane = tid & 63;
    const int srow = tid >> 1, shalf = tid & 1;   // 2 staging threads per row

    // ---- all neighbor indices up front (independent loads, no chain) ----
    int g[NTAP];
    {
        int p = pc[base + srow];
        int x = p & 1023, y = (p >> 10) & 1023, b = p >> 20;
        int cell = b*HW + y*WG + x;
        #pragma unroll
        for (int t = 0; t < 9; ++t) {
            int dy = t/3 - 1, dx = t%3 - 1;
            int ny = y + dy, nx = x + dx;
            g[t] = (ny >= 0 && ny < HG && nx >= 0 && nx < WG) ? sgrid[cell + dy*WG + dx] : -1;
        }
        if (FINAL) g[NTAP-1] = base + srow;   // residual tap: identity gather
    }

    f32x4 acc[2][4];
    f32x4 accR[2][4];
    #pragma unroll
    for (int i = 0; i < 2; ++i)
        #pragma unroll
        for (int j = 0; j < 4; ++j) {
            acc[i][j]  = (f32x4){0.f, 0.f, 0.f, 0.f};
            accR[i][j] = (f32x4){0.f, 0.f, 0.f, 0.f};
        }

    // staging addresses (invariant across taps)
    uint4* adst = (uint4*)(As + srow*LDA + shalf*32);
    const int e0 = tid, e1 = tid + 256;                    // uint4 elems of the 64x64 tap
    const int n0 = (e0*8) >> 6, k0 = (e0*8) & 63;
    const int n1 = (e1*8) >> 6, k1 = (e1*8) & 63;

    // prefetch registers
    uint4 av[4], bv[2];
    bool vld;

    auto prefetch = [&](int t) {
        int gg = g[t];
        const __hip_bfloat16* sp = (FINAL && t == NTAP-1) ? idsrc : src;
        vld = gg >= 0;
        const uint4* p = (const uint4*)(sp + (long)(gg < 0 ? 0 : gg)*64 + shalf*32);
        av[0] = p[0]; av[1] = p[1]; av[2] = p[2]; av[3] = p[3];
        const uint4* wp = (const uint4*)(wT + t*4096);
        bv[0] = wp[e0]; bv[1] = wp[e1];
    };

    prefetch(0);

    #pragma unroll
    for (int t = 0; t < NTAP; ++t) {
        if (t) __syncthreads();    // WAR: prev tap's LDS reads done

        const uint4 z = make_uint4(0u,0u,0u,0u);
        adst[0] = vld ? av[0] : z;
        adst[1] = vld ? av[1] : z;
        adst[2] = vld ? av[2] : z;
        adst[3] = vld ? av[3] : z;
        *(uint4*)(Bs + n0*LDB + k0) = bv[0];
        *(uint4*)(Bs + n1*LDB + k1) = bv[1];
        __syncthreads();

        if (t + 1 < NTAP) prefetch(t + 1);   // in flight during MFMA below

        f32x4 (&ac)[2][4] = (FINAL && t == NTAP-1) ? accR : acc;
        #pragma unroll
        for (int ks = 0; ks < 2; ++ks) {
            int kb = ks*32 + (lane >> 4)*8;
            bf16x8 a0 = *(const bf16x8*)(As + (wave*32      + (lane & 15))*LDA + kb);
            bf16x8 a1 = *(const bf16x8*)(As + (wave*32 + 16 + (lane & 15))*LDA + kb);
            bf16x8 b0 = *(const bf16x8*)(Bs + ( 0 + (lane & 15))*LDB + kb);
            bf16x8 b1 = *(const bf16x8*)(Bs + (16 + (lane & 15))*LDB + kb);
            bf16x8 b2 = *(const bf16x8*)(Bs + (32 + (lane & 15))*LDB + kb);
            bf16x8 b3 = *(const bf16x8*)(Bs + (48 + (lane & 15))*LDB + kb);
            ac[0][0] = __builtin_amdgcn_mfma_f32_16x16x32_bf16(a0, b0, ac[0][0], 0, 0, 0);
            ac[0][1] = __builtin_amdgcn_mfma_f32_16x16x32_bf16(a0, b1, ac[0][1], 0, 0, 0);
            ac[0][2] = __builtin_amdgcn_mfma_f32_16x16x32_bf16(a0, b2, ac[0][2], 0, 0, 0);
            ac[0][3] = __builtin_amdgcn_mfma_f32_16x16x32_bf16(a0, b3, ac[0][3], 0, 0, 0);
            ac[1][0] = __builtin_amdgcn_mfma_f32_16x16x32_bf16(a1, b0, ac[1][0], 0, 0, 0);
            ac[1][1] = __builtin_amdgcn_mfma_f32_16x16x32_bf16(a1, b1, ac[1][1], 0, 0, 0);
            ac[1][2] = __builtin_amdgcn_mfma_f32_16x16x32_bf16(a1, b2, ac[1][2], 0, 0, 0);
            ac[1][3] = __builtin_amdgcn_mfma_f32_16x16x32_bf16(a1, b3, ac[1][3], 0, 0, 0);
        }
    }

    // ---- epilogue: bias + relu (+ residual for FINAL) + store ----
    const int col = lane & 15, quad = lane >> 4;
    #pragma unroll
    for (int cb = 0; cb < 4; ++cb) {
        float bv2 = bias[cb*16 + col];
        #pragma unroll
        for (int mb = 0; mb < 2; ++mb) {
            #pragma unroll
            for (int r = 0; r < 4; ++r) {
                float v = acc[mb][cb][r] + bv2;
                v = v > 0.f ? v : 0.f;
                long row = base + wave*32 + mb*16 + quad*4 + r;
                int  c   = cb*16 + col;
                if (FINAL) {
                    v += accR[mb][cb][r];      // residual AFTER inner relu
                    v = v > 0.f ? v : 0.f;
                    out_f[row*64 + c] = v;
                } else {
                    out_bf[row*64 + c] = __float2bfloat16(v);
                }
            }
        }
    }
}

// ---------------- launch ----------------

extern "C" void kernel_launch(void* const* d_in, const int* in_sizes, int n_in,
                              void* d_out, int out_size, void* d_ws, size_t ws_size,
                              hipStream_t stream) {
    const float* features = (const float*)d_in[0];
    const int*   coords   = (const int*)d_in[1];
    const float* w1 = (const float*)d_in[2];
    const float* b1 = (const float*)d_in[3];
    const float* w2 = (const float*)d_in[4];
    const float* b2 = (const float*)d_in[5];
    const float* wd = (const float*)d_in[6];
    float* out = (float*)d_out;

    char* ws = (char*)d_ws;
    int*            sgrid = (int*)ws;                           // 3,276,800 B
    int*            pc    = (int*)(ws + 3276800);               // 1,638,400 B
    __hip_bfloat16* fb    = (__hip_bfloat16*)(ws + 4915200);    // 52,428,800 B
    __hip_bfloat16* y1    = (__hip_bfloat16*)(ws + 57344000);   // 52,428,800 B
    __hip_bfloat16* wc1   = (__hip_bfloat16*)(ws + 109772800);  // 73,728 B
    __hip_bfloat16* wc2   = (__hip_bfloat16*)(ws + 109846528);  // 81,920 B
    // total 109,928,448 B

    hipMemsetAsync(sgrid, 0xFF, (size_t)HW * 2 * sizeof(int), stream);   // grid = -1

    scatter_kernel  <<<1600,  256, 0, stream>>>(coords, sgrid, pc);
    cast_feat_kernel<<<12800, 256, 0, stream>>>(features, fb);
    cast_w_kernel   <<<304,   256, 0, stream>>>(w1, w2, wd, wc1, wc2);

    conv_kernel<9,  false><<<3200, 256, 0, stream>>>(fb, fb, pc, sgrid, wc1, b1, y1, nullptr);
    conv_kernel<10, true ><<<3200, 256, 0, stream>>>(y1, fb, pc, sgrid, wc2, b2, nullptr, out);
}

// Round 4
// 571.793 us; speedup vs baseline: 1.2632x; 1.2632x over previous
//
#include <hip/hip_runtime.h>
#include <hip/hip_bf16.h>
#include <stdint.h>

#define NP 409600
#define HG 640
#define WG 640
#define HW (HG*WG)

typedef __bf16 bf16x8 __attribute__((ext_vector_type(8)));
typedef float f32x4 __attribute__((ext_vector_type(4)));

// ---------------- prep kernels ----------------

// scatter point index into dense grid AND emit packed coords (b<<20|y<<10|x)
__global__ void scatter_kernel(const int* __restrict__ coords, int* __restrict__ sgrid,
                               int* __restrict__ pc) {
    int i = blockIdx.x * 256 + threadIdx.x;   // grid sized exactly NP
    int b = coords[3*i], y = coords[3*i+1], x = coords[3*i+2];
    sgrid[b*HW + y*WG + x] = i;
    pc[i] = (b << 20) | (y << 10) | x;
}

__global__ void cast_feat_kernel(const float* __restrict__ f, __hip_bfloat16* __restrict__ fb) {
    long i = (long)(blockIdx.x * 256 + threadIdx.x) * 8;   // grid covers NP*64 exactly
    float4 a = *(const float4*)(f + i);
    float4 b = *(const float4*)(f + i + 4);
    union { uint4 q; __hip_bfloat16 h[8]; } u;
    u.h[0] = __float2bfloat16(a.x); u.h[1] = __float2bfloat16(a.y);
    u.h[2] = __float2bfloat16(a.z); u.h[3] = __float2bfloat16(a.w);
    u.h[4] = __float2bfloat16(b.x); u.h[5] = __float2bfloat16(b.y);
    u.h[6] = __float2bfloat16(b.z); u.h[7] = __float2bfloat16(b.w);
    *(uint4*)(fb + i) = u.q;
}

// weights pre-cast to bf16, transposed to [tap][n=out_ch][k=in_ch]
__global__ void cast_w_kernel(const float* __restrict__ w1, const float* __restrict__ w2,
                              const float* __restrict__ wd,
                              __hip_bfloat16* __restrict__ wc1, __hip_bfloat16* __restrict__ wc2) {
    int i = blockIdx.x * 256 + threadIdx.x;   // grid = 77824 threads exactly
    if (i < 9*4096) {
        int t = i >> 12, r = i & 4095, n = r >> 6, k = r & 63;
        wc1[i] = __float2bfloat16(w1[(t << 12) + (k << 6) + n]);
    }
    int j = i - 9*4096;
    if (j >= 0 && j < 10*4096) {
        int t = j >> 12, r = j & 4095, n = r >> 6, k = r & 63;
        float v = (t < 9) ? w2[(t << 12) + (k << 6) + n] : wd[(k << 6) + n];
        wc2[j] = __float2bfloat16(v);
    }
}

// ---------------- gather-GEMM conv kernel (software-pipelined) ----------------
// Tile: 128 rows x 64 cols, 256 threads = 4 waves.
// Per tap: [barrier] -> LDS store (prefetched regs) -> [barrier] -> issue
// prefetch for tap t+1 -> MFMA tap t. Gather latency hides behind MFMA.
// NOTE: accumulator selection MUST be a compile-time parameter call, never a
// runtime-selected reference (R3: ternary-reference defeated SROA -> scratch
// spill -> 940 MB WRITE_SIZE, 3.5x regression). Prefetch buffers are named
// scalars for the same reason.

#define LDA 72
#define LDB 72

template<int NTAP, bool FINAL>
__launch_bounds__(256)
__global__ void conv_kernel(const __hip_bfloat16* __restrict__ src,
                            const __hip_bfloat16* __restrict__ idsrc,
                            const int* __restrict__ pc,
                            const int* __restrict__ sgrid,
                            const __hip_bfloat16* __restrict__ wT,   // [NTAP][64][64] (n,k)
                            const float* __restrict__ bias,
                            __hip_bfloat16* __restrict__ out_bf,
                            float* __restrict__ out_f) {
    __shared__ __align__(16) __hip_bfloat16 As[128 * LDA];
    __shared__ __align__(16) __hip_bfloat16 Bs[64 * LDB];

    const int tid  = threadIdx.x;
    const int base = blockIdx.x * 128;
    const int wave = tid >> 6, lane = tid & 63;
    const int srow = tid >> 1, shalf = tid & 1;   // 2 staging threads per row

    // ---- all 9 neighbor indices up front (independent loads, no chain) ----
    int g[9];
    {
        int p = pc[base + srow];
        int x = p & 1023, y = (p >> 10) & 1023, b = p >> 20;
        int cell = b*HW + y*WG + x;
        #pragma unroll
        for (int t = 0; t < 9; ++t) {
            int dy = t/3 - 1, dx = t%3 - 1;
            int ny = y + dy, nx = x + dx;
            g[t] = (ny >= 0 && ny < HG && nx >= 0 && nx < WG) ? sgrid[cell + dy*WG + dx] : -1;
        }
    }

    f32x4 acc[2][4];
    f32x4 accR[2][4];
    #pragma unroll
    for (int i = 0; i < 2; ++i)
        #pragma unroll
        for (int j = 0; j < 4; ++j) {
            acc[i][j]  = (f32x4){0.f, 0.f, 0.f, 0.f};
            accR[i][j] = (f32x4){0.f, 0.f, 0.f, 0.f};
        }

    // staging addresses (invariant across taps)
    uint4* adst = (uint4*)(As + srow*LDA + shalf*32);
    const int e0 = tid, e1 = tid + 256;                    // uint4 elems of the 64x64 tap
    const int n0 = (e0*8) >> 6, k0 = (e0*8) & 63;
    const int n1 = (e1*8) >> 6, k1 = (e1*8) & 63;

    // prefetch registers (named scalars — must not spill)
    uint4 av0, av1, av2, av3, bv0, bv1;
    bool vld;

    auto prefetch = [&](int t, const __hip_bfloat16* sp, int gg) {
        vld = gg >= 0;
        const uint4* p = (const uint4*)(sp + (long)(gg < 0 ? 0 : gg)*64 + shalf*32);
        av0 = p[0]; av1 = p[1]; av2 = p[2]; av3 = p[3];
        const uint4* wp = (const uint4*)(wT + t*4096);
        bv0 = wp[e0]; bv1 = wp[e1];
    };

    auto do_mfma = [&](f32x4 (&ac)[2][4]) {
        #pragma unroll
        for (int ks = 0; ks < 2; ++ks) {
            int kb = ks*32 + (lane >> 4)*8;
            bf16x8 a0 = *(const bf16x8*)(As + (wave*32      + (lane & 15))*LDA + kb);
            bf16x8 a1 = *(const bf16x8*)(As + (wave*32 + 16 + (lane & 15))*LDA + kb);
            bf16x8 b0 = *(const bf16x8*)(Bs + ( 0 + (lane & 15))*LDB + kb);
            bf16x8 b1 = *(const bf16x8*)(Bs + (16 + (lane & 15))*LDB + kb);
            bf16x8 b2 = *(const bf16x8*)(Bs + (32 + (lane & 15))*LDB + kb);
            bf16x8 b3 = *(const bf16x8*)(Bs + (48 + (lane & 15))*LDB + kb);
            ac[0][0] = __builtin_amdgcn_mfma_f32_16x16x32_bf16(a0, b0, ac[0][0], 0, 0, 0);
            ac[0][1] = __builtin_amdgcn_mfma_f32_16x16x32_bf16(a0, b1, ac[0][1], 0, 0, 0);
            ac[0][2] = __builtin_amdgcn_mfma_f32_16x16x32_bf16(a0, b2, ac[0][2], 0, 0, 0);
            ac[0][3] = __builtin_amdgcn_mfma_f32_16x16x32_bf16(a0, b3, ac[0][3], 0, 0, 0);
            ac[1][0] = __builtin_amdgcn_mfma_f32_16x16x32_bf16(a1, b0, ac[1][0], 0, 0, 0);
            ac[1][1] = __builtin_amdgcn_mfma_f32_16x16x32_bf16(a1, b1, ac[1][1], 0, 0, 0);
            ac[1][2] = __builtin_amdgcn_mfma_f32_16x16x32_bf16(a1, b2, ac[1][2], 0, 0, 0);
            ac[1][3] = __builtin_amdgcn_mfma_f32_16x16x32_bf16(a1, b3, ac[1][3], 0, 0, 0);
        }
    };

    prefetch(0, src, g[0]);

    #pragma unroll
    for (int t = 0; t < NTAP; ++t) {
        if (t) __syncthreads();    // WAR: prev tap's LDS reads done

        const uint4 z = make_uint4(0u,0u,0u,0u);
        adst[0] = vld ? av0 : z;
        adst[1] = vld ? av1 : z;
        adst[2] = vld ? av2 : z;
        adst[3] = vld ? av3 : z;
        *(uint4*)(Bs + n0*LDB + k0) = bv0;
        *(uint4*)(Bs + n1*LDB + k1) = bv1;
        __syncthreads();

        if (t + 1 < NTAP) {        // issue next tap's gather during MFMA
            if (FINAL && t + 1 == NTAP - 1) prefetch(t + 1, idsrc, base + srow);
            else                            prefetch(t + 1, src, g[t + 1]);
        }

        if (FINAL && t == NTAP - 1) do_mfma(accR);
        else                        do_mfma(acc);
    }

    // ---- epilogue: bias + relu (+ residual for FINAL) + store ----
    const int col = lane & 15, quad = lane >> 4;
    #pragma unroll
    for (int cb = 0; cb < 4; ++cb) {
        float bv2 = bias[cb*16 + col];
        #pragma unroll
        for (int mb = 0; mb < 2; ++mb) {
            #pragma unroll
            for (int r = 0; r < 4; ++r) {
                float v = acc[mb][cb][r] + bv2;
                v = v > 0.f ? v : 0.f;
                long row = base + wave*32 + mb*16 + quad*4 + r;
                int  c   = cb*16 + col;
                if (FINAL) {
                    v += accR[mb][cb][r];      // residual AFTER inner relu
                    v = v > 0.f ? v : 0.f;
                    out_f[row*64 + c] = v;
                } else {
                    out_bf[row*64 + c] = __float2bfloat16(v);
                }
            }
        }
    }
}

// ---------------- launch ----------------

extern "C" void kernel_launch(void* const* d_in, const int* in_sizes, int n_in,
                              void* d_out, int out_size, void* d_ws, size_t ws_size,
                              hipStream_t stream) {
    const float* features = (const float*)d_in[0];
    const int*   coords   = (const int*)d_in[1];
    const float* w1 = (const float*)d_in[2];
    const float* b1 = (const float*)d_in[3];
    const float* w2 = (const float*)d_in[4];
    const float* b2 = (const float*)d_in[5];
    const float* wd = (const float*)d_in[6];
    float* out = (float*)d_out;

    char* ws = (char*)d_ws;
    int*            sgrid = (int*)ws;                           // 3,276,800 B
    int*            pc    = (int*)(ws + 3276800);               // 1,638,400 B
    __hip_bfloat16* fb    = (__hip_bfloat16*)(ws + 4915200);    // 52,428,800 B
    __hip_bfloat16* y1    = (__hip_bfloat16*)(ws + 57344000);   // 52,428,800 B
    __hip_bfloat16* wc1   = (__hip_bfloat16*)(ws + 109772800);  // 73,728 B
    __hip_bfloat16* wc2   = (__hip_bfloat16*)(ws + 109846528);  // 81,920 B
    // total 109,928,448 B

    hipMemsetAsync(sgrid, 0xFF, (size_t)HW * 2 * sizeof(int), stream);   // grid = -1

    scatter_kernel  <<<1600,  256, 0, stream>>>(coords, sgrid, pc);
    cast_feat_kernel<<<12800, 256, 0, stream>>>(features, fb);
    cast_w_kernel   <<<304,   256, 0, stream>>>(w1, w2, wd, wc1, wc2);

    conv_kernel<9,  false><<<3200, 256, 0, stream>>>(fb, fb, pc, sgrid, wc1, b1, y1, nullptr);
    conv_kernel<10, true ><<<3200, 256, 0, stream>>>(y1, fb, pc, sgrid, wc2, b2, nullptr, out);
}

// Round 5
// 570.010 us; speedup vs baseline: 1.2672x; 1.0031x over previous
//
#include <hip/hip_runtime.h>
#include <hip/hip_bf16.h>
#include <stdint.h>

#define NP 409600
#define HG 640
#define WG 640
#define HW (HG*WG)

typedef __bf16 bf16x8 __attribute__((ext_vector_type(8)));
typedef float f32x4 __attribute__((ext_vector_type(4)));

// ---------------- prep kernels ----------------

// scatter point index into dense grid AND emit packed coords (b<<20|y<<10|x)
__global__ void scatter_kernel(const int* __restrict__ coords, int* __restrict__ sgrid,
                               int* __restrict__ pc) {
    int i = blockIdx.x * 256 + threadIdx.x;   // grid sized exactly NP
    int b = coords[3*i], y = coords[3*i+1], x = coords[3*i+2];
    sgrid[b*HW + y*WG + x] = i;
    pc[i] = (b << 20) | (y << 10) | x;
}

__global__ void cast_feat_kernel(const float* __restrict__ f, __hip_bfloat16* __restrict__ fb) {
    long i = (long)(blockIdx.x * 256 + threadIdx.x) * 8;   // grid covers NP*64 exactly
    float4 a = *(const float4*)(f + i);
    float4 b = *(const float4*)(f + i + 4);
    union { uint4 q; __hip_bfloat16 h[8]; } u;
    u.h[0] = __float2bfloat16(a.x); u.h[1] = __float2bfloat16(a.y);
    u.h[2] = __float2bfloat16(a.z); u.h[3] = __float2bfloat16(a.w);
    u.h[4] = __float2bfloat16(b.x); u.h[5] = __float2bfloat16(b.y);
    u.h[6] = __float2bfloat16(b.z); u.h[7] = __float2bfloat16(b.w);
    *(uint4*)(fb + i) = u.q;
}

// weights pre-cast to bf16, transposed to [tap][n=out_ch][k=in_ch]
__global__ void cast_w_kernel(const float* __restrict__ w1, const float* __restrict__ w2,
                              const float* __restrict__ wd,
                              __hip_bfloat16* __restrict__ wc1, __hip_bfloat16* __restrict__ wc2) {
    int i = blockIdx.x * 256 + threadIdx.x;   // grid = 77824 threads exactly
    if (i < 9*4096) {
        int t = i >> 12, r = i & 4095, n = r >> 6, k = r & 63;
        wc1[i] = __float2bfloat16(w1[(t << 12) + (k << 6) + n]);
    }
    int j = i - 9*4096;
    if (j >= 0 && j < 10*4096) {
        int t = j >> 12, r = j & 4095, n = r >> 6, k = r & 63;
        float v = (t < 9) ? w2[(t << 12) + (k << 6) + n] : wd[(k << 6) + n];
        wc2[j] = __float2bfloat16(v);
    }
}

// ---------------- gather-GEMM conv kernel (software-pipelined) ----------------
// Tile: 128 rows x 64 cols, 256 threads = 4 waves.
// Per tap: [barrier] -> LDS store (prefetched regs) -> [barrier] -> issue
// prefetch for tap t+1 -> MFMA tap t.
// SINGLE accumulator: for FINAL, taps 0..8 = conv2; then acc = relu(acc+b2)
// in-register; tap 9 (identity @ wd) continues accumulating into the SAME acc
// — MFMA's C-operand performs "+ residual" for free. This removes the 32-reg
// second accumulator that caused scratch spills in R3/R4 (WRITE_SIZE 5-9x).

#define LDA 72
#define LDB 72

template<int NTAP, bool FINAL>
__launch_bounds__(256)
__global__ void conv_kernel(const __hip_bfloat16* __restrict__ src,
                            const __hip_bfloat16* __restrict__ idsrc,
                            const int* __restrict__ pc,
                            const int* __restrict__ sgrid,
                            const __hip_bfloat16* __restrict__ wT,   // [NTAP][64][64] (n,k)
                            const float* __restrict__ bias,
                            __hip_bfloat16* __restrict__ out_bf,
                            float* __restrict__ out_f) {
    __shared__ __align__(16) __hip_bfloat16 As[128 * LDA];
    __shared__ __align__(16) __hip_bfloat16 Bs[64 * LDB];

    const int tid  = threadIdx.x;
    const int base = blockIdx.x * 128;
    const int wave = tid >> 6, lane = tid & 63;
    const int srow = tid >> 1, shalf = tid & 1;   // 2 staging threads per row

    // per-lane bias values (col = cb*16 + (lane&15))
    const int col = lane & 15, quad = lane >> 4;
    float bz0 = bias[ 0 + col], bz1 = bias[16 + col],
          bz2 = bias[32 + col], bz3 = bias[48 + col];

    // ---- all 9 neighbor indices up front (independent loads, no chain) ----
    int g[9];
    {
        int p = pc[base + srow];
        int x = p & 1023, y = (p >> 10) & 1023, b = p >> 20;
        int cell = b*HW + y*WG + x;
        #pragma unroll
        for (int t = 0; t < 9; ++t) {
            int dy = t/3 - 1, dx = t%3 - 1;
            int ny = y + dy, nx = x + dx;
            g[t] = (ny >= 0 && ny < HG && nx >= 0 && nx < WG) ? sgrid[cell + dy*WG + dx] : -1;
        }
    }

    f32x4 acc[2][4];
    #pragma unroll
    for (int i = 0; i < 2; ++i)
        #pragma unroll
        for (int j = 0; j < 4; ++j) acc[i][j] = (f32x4){0.f, 0.f, 0.f, 0.f};

    // staging addresses (invariant across taps)
    uint4* adst = (uint4*)(As + srow*LDA + shalf*32);
    const int e0 = tid, e1 = tid + 256;                    // uint4 elems of the 64x64 tap
    const int n0 = (e0*8) >> 6, k0 = (e0*8) & 63;
    const int n1 = (e1*8) >> 6, k1 = (e1*8) & 63;

    // prefetch registers (named scalars — must not spill)
    uint4 av0, av1, av2, av3, bv0, bv1;
    bool vld;

    // prefetch tap 0
    {
        int gg = g[0];
        vld = gg >= 0;
        const uint4* p = (const uint4*)(src + (long)(gg < 0 ? 0 : gg)*64 + shalf*32);
        av0 = p[0]; av1 = p[1]; av2 = p[2]; av3 = p[3];
        const uint4* wp = (const uint4*)(wT);
        bv0 = wp[e0]; bv1 = wp[e1];
    }

    #pragma unroll
    for (int t = 0; t < NTAP; ++t) {
        if (t) __syncthreads();    // WAR: prev tap's LDS reads done

        const uint4 z = make_uint4(0u,0u,0u,0u);
        adst[0] = vld ? av0 : z;
        adst[1] = vld ? av1 : z;
        adst[2] = vld ? av2 : z;
        adst[3] = vld ? av3 : z;
        *(uint4*)(Bs + n0*LDB + k0) = bv0;
        *(uint4*)(Bs + n1*LDB + k1) = bv1;
        __syncthreads();

        if (t + 1 < NTAP) {        // issue next tap's gather during MFMA
            const bool idt = (FINAL && t + 1 == NTAP - 1);
            int gg = idt ? (base + srow) : g[t + 1];
            const __hip_bfloat16* sp = idt ? idsrc : src;
            vld = gg >= 0;
            const uint4* p = (const uint4*)(sp + (long)(gg < 0 ? 0 : gg)*64 + shalf*32);
            av0 = p[0]; av1 = p[1]; av2 = p[2]; av3 = p[3];
            const uint4* wp = (const uint4*)(wT + (t + 1)*4096);
            bv0 = wp[e0]; bv1 = wp[e1];
        }

        // FINAL: before the residual tap, fold bias+relu into acc so the
        // residual MFMA accumulates on top of relu(conv2+b2).
        if (FINAL && t == NTAP - 1) {
            #pragma unroll
            for (int mb = 0; mb < 2; ++mb) {
                #pragma unroll
                for (int r = 0; r < 4; ++r) {
                    float v0 = acc[mb][0][r] + bz0; acc[mb][0][r] = v0 > 0.f ? v0 : 0.f;
                    float v1 = acc[mb][1][r] + bz1; acc[mb][1][r] = v1 > 0.f ? v1 : 0.f;
                    float v2 = acc[mb][2][r] + bz2; acc[mb][2][r] = v2 > 0.f ? v2 : 0.f;
                    float v3 = acc[mb][3][r] + bz3; acc[mb][3][r] = v3 > 0.f ? v3 : 0.f;
                }
            }
        }

        #pragma unroll
        for (int ks = 0; ks < 2; ++ks) {
            int kb = ks*32 + quad*8;
            bf16x8 a0 = *(const bf16x8*)(As + (wave*32      + col)*LDA + kb);
            bf16x8 a1 = *(const bf16x8*)(As + (wave*32 + 16 + col)*LDA + kb);
            bf16x8 b0 = *(const bf16x8*)(Bs + ( 0 + col)*LDB + kb);
            bf16x8 b1 = *(const bf16x8*)(Bs + (16 + col)*LDB + kb);
            bf16x8 b2 = *(const bf16x8*)(Bs + (32 + col)*LDB + kb);
            bf16x8 b3 = *(const bf16x8*)(Bs + (48 + col)*LDB + kb);
            acc[0][0] = __builtin_amdgcn_mfma_f32_16x16x32_bf16(a0, b0, acc[0][0], 0, 0, 0);
            acc[0][1] = __builtin_amdgcn_mfma_f32_16x16x32_bf16(a0, b1, acc[0][1], 0, 0, 0);
            acc[0][2] = __builtin_amdgcn_mfma_f32_16x16x32_bf16(a0, b2, acc[0][2], 0, 0, 0);
            acc[0][3] = __builtin_amdgcn_mfma_f32_16x16x32_bf16(a0, b3, acc[0][3], 0, 0, 0);
            acc[1][0] = __builtin_amdgcn_mfma_f32_16x16x32_bf16(a1, b0, acc[1][0], 0, 0, 0);
            acc[1][1] = __builtin_amdgcn_mfma_f32_16x16x32_bf16(a1, b1, acc[1][1], 0, 0, 0);
            acc[1][2] = __builtin_amdgcn_mfma_f32_16x16x32_bf16(a1, b2, acc[1][2], 0, 0, 0);
            acc[1][3] = __builtin_amdgcn_mfma_f32_16x16x32_bf16(a1, b3, acc[1][3], 0, 0, 0);
        }
    }

    // ---- epilogue ----
    #pragma unroll
    for (int cb = 0; cb < 4; ++cb) {
        float bv2 = (cb == 0) ? bz0 : (cb == 1) ? bz1 : (cb == 2) ? bz2 : bz3;
        #pragma unroll
        for (int mb = 0; mb < 2; ++mb) {
            #pragma unroll
            for (int r = 0; r < 4; ++r) {
                float v = acc[mb][cb][r];
                if (!FINAL) v += bv2;          // FINAL already folded bias
                v = v > 0.f ? v : 0.f;
                long row = base + wave*32 + mb*16 + quad*4 + r;
                int  c   = cb*16 + col;
                if (FINAL) out_f[row*64 + c] = v;
                else       out_bf[row*64 + c] = __float2bfloat16(v);
            }
        }
    }
}

// ---------------- launch ----------------

extern "C" void kernel_launch(void* const* d_in, const int* in_sizes, int n_in,
                              void* d_out, int out_size, void* d_ws, size_t ws_size,
                              hipStream_t stream) {
    const float* features = (const float*)d_in[0];
    const int*   coords   = (const int*)d_in[1];
    const float* w1 = (const float*)d_in[2];
    const float* b1 = (const float*)d_in[3];
    const float* w2 = (const float*)d_in[4];
    const float* b2 = (const float*)d_in[5];
    const float* wd = (const float*)d_in[6];
    float* out = (float*)d_out;

    char* ws = (char*)d_ws;
    int*            sgrid = (int*)ws;                           // 3,276,800 B
    int*            pc    = (int*)(ws + 3276800);               // 1,638,400 B
    __hip_bfloat16* fb    = (__hip_bfloat16*)(ws + 4915200);    // 52,428,800 B
    __hip_bfloat16* y1    = (__hip_bfloat16*)(ws + 57344000);   // 52,428,800 B
    __hip_bfloat16* wc1   = (__hip_bfloat16*)(ws + 109772800);  // 73,728 B
    __hip_bfloat16* wc2   = (__hip_bfloat16*)(ws + 109846528);  // 81,920 B
    // total 109,928,448 B

    hipMemsetAsync(sgrid, 0xFF, (size_t)HW * 2 * sizeof(int), stream);   // grid = -1

    scatter_kernel  <<<1600,  256, 0, stream>>>(coords, sgrid, pc);
    cast_feat_kernel<<<12800, 256, 0, stream>>>(features, fb);
    cast_w_kernel   <<<304,   256, 0, stream>>>(w1, w2, wd, wc1, wc2);

    conv_kernel<9,  false><<<3200, 256, 0, stream>>>(fb, fb, pc, sgrid, wc1, b1, y1, nullptr);
    conv_kernel<10, true ><<<3200, 256, 0, stream>>>(y1, fb, pc, sgrid, wc2, b2, nullptr, out);
}